// Round 1
// baseline (257.188 us; speedup 1.0000x reference)
//
#include <hip/hip_runtime.h>
#include <hip/hip_bf16.h>
#include <cstdint>
#include <cstddef>

#define DEV static __device__ __forceinline__

typedef __bf16 bf16x8 __attribute__((ext_vector_type(8)));
typedef float f32x4 __attribute__((ext_vector_type(4)));
typedef unsigned short ushort8v __attribute__((ext_vector_type(8)));
typedef unsigned short u16;

static constexpr int BATCH = 2, SEQ = 2048, DM = 1024, NH = 16, DH = 64;
static constexpr int Kdim = 1024;

DEV u16 f2b(float f) {  // f32 -> bf16 RNE
  uint32_t u = __builtin_bit_cast(uint32_t, f);
  u += 0x7FFFu + ((u >> 16) & 1u);
  return (u16)(u >> 16);
}
DEV float b2f(u16 v) { return __builtin_bit_cast(float, (uint32_t)v << 16); }

DEV void gload_lds16(const void* g, void* l) {
  __builtin_amdgcn_global_load_lds((const __attribute__((address_space(1))) void*)g,
                                   (__attribute__((address_space(3))) void*)l, 16, 0, 0);
}

// ---------------- cast f32 -> bf16 (vectorized x4) ----------------
__global__ __launch_bounds__(256) void cast_kernel(const float* __restrict__ src,
                                                   u16* __restrict__ dst, int n4) {
  int i = blockIdx.x * blockDim.x + threadIdx.x;
  const int stride = gridDim.x * blockDim.x;
  for (; i < n4; i += stride) {
    float4 v = ((const float4*)src)[i];
    ushort4 o;
    o.x = f2b(v.x); o.y = f2b(v.y); o.z = f2b(v.z); o.w = f2b(v.w);
    ((ushort4*)dst)[i] = o;
  }
}

// ---------------- GEMM: C[M=4096,1024] = A[4096,1024] * B[1024,1024]^T ----------------
// 128x128 tile, BK=32, 4 waves (2x2), 16x16x32 bf16 MFMA, global_load_lds staging.
template <bool OUTF32>
DEV void gemm_core(const u16* __restrict__ A, const u16* __restrict__ Bm, void* __restrict__ Cout) {
  __shared__ u16 As[128 * 32], Bs[128 * 32];
  const int tid = threadIdx.x;
  const int lane = tid & 63, wid = tid >> 6;
  const int m0 = blockIdx.y * 128, n0 = blockIdx.x * 128;
  const int wr = (wid >> 1) * 64, wc = (wid & 1) * 64;
  const int frow = lane & 15, fgrp = lane >> 4;
  f32x4 acc[4][4] = {};

  // staging: 512 chunks of 16B per tile; chunk c: r=c>>2, cc=c&3; source col swizzled by r&3
  const int c0 = tid, c1 = tid + 256;
  const int r0 = c0 >> 2, s80 = (c0 & 3) ^ (r0 & 3);
  const int r1 = c1 >> 2, s81 = (c1 & 3) ^ (r1 & 3);
  const size_t gA0 = (size_t)(m0 + r0) * Kdim + s80 * 8;
  const size_t gA1 = (size_t)(m0 + r1) * Kdim + s81 * 8;
  const size_t gB0 = (size_t)(n0 + r0) * Kdim + s80 * 8;
  const size_t gB1 = (size_t)(n0 + r1) * Kdim + s81 * 8;
  u16* ldsA0 = As + wid * 512;        u16* ldsA1 = As + wid * 512 + 2048;
  u16* ldsB0 = Bs + wid * 512;        u16* ldsB1 = Bs + wid * 512 + 2048;

  for (int kt = 0; kt < Kdim / 32; ++kt) {
    const int k0 = kt * 32;
    __syncthreads();
    gload_lds16(A + gA0 + k0, ldsA0);
    gload_lds16(A + gA1 + k0, ldsA1);
    gload_lds16(Bm + gB0 + k0, ldsB0);
    gload_lds16(Bm + gB1 + k0, ldsB1);
    __syncthreads();
    bf16x8 af[4], bfr[4];
#pragma unroll
    for (int i = 0; i < 4; ++i) {
      const int ra = wr + i * 16 + frow;
      const int rb = wc + i * 16 + frow;
      af[i]  = *(const bf16x8*)((const char*)As + ra * 64 + ((fgrp ^ (ra & 3)) * 16));
      bfr[i] = *(const bf16x8*)((const char*)Bs + rb * 64 + ((fgrp ^ (rb & 3)) * 16));
    }
#pragma unroll
    for (int mi = 0; mi < 4; ++mi)
#pragma unroll
      for (int ni = 0; ni < 4; ++ni)
        acc[mi][ni] = __builtin_amdgcn_mfma_f32_16x16x32_bf16(af[mi], bfr[ni], acc[mi][ni], 0, 0, 0);
  }
  const int colb = n0 + wc + frow;
  const int rowb = m0 + wr + fgrp * 4;
#pragma unroll
  for (int mi = 0; mi < 4; ++mi)
#pragma unroll
    for (int ni = 0; ni < 4; ++ni)
#pragma unroll
      for (int r = 0; r < 4; ++r) {
        const int row = rowb + mi * 16 + r;
        const int col = colb + ni * 16;
        const float v = acc[mi][ni][r];
        if (OUTF32) ((float*)Cout)[(size_t)row * DM + col] = v;
        else        ((u16*)Cout)[(size_t)row * DM + col] = f2b(v);
      }
}

__global__ __launch_bounds__(256) void gemm_qkv(const u16* __restrict__ xb,
    const u16* __restrict__ wq, const u16* __restrict__ wk, const u16* __restrict__ wv,
    u16* __restrict__ Qb, u16* __restrict__ Kb, u16* __restrict__ Vb) {
  const u16* W; u16* O;
  if (blockIdx.z == 0)      { W = wq; O = Qb; }
  else if (blockIdx.z == 1) { W = wk; O = Kb; }
  else                      { W = wv; O = Vb; }
  gemm_core<false>(xb, W, O);
}

__global__ __launch_bounds__(256) void gemm_o(const u16* __restrict__ attb,
                                              const u16* __restrict__ wob,
                                              float* __restrict__ out) {
  gemm_core<true>(attb, wob, out);
}

// ---------------- RoPE on Q and K (in place, bf16), folds 1/8 scale into Q ----------------
__global__ __launch_bounds__(256) void rope_kernel(u16* __restrict__ Q, u16* __restrict__ K,
                                                   const int* __restrict__ pos, int npairs) {
  int i = blockIdx.x * blockDim.x + threadIdx.x;
  const int stride = gridDim.x * blockDim.x;
  for (; i < npairs; i += stride) {
    const int j = i & 31;
    const int rest = i >> 5;                    // (b*S+s)*16 + h
    const int bs = rest >> 4;                   // b*S+s
    const int s = bs & (SEQ - 1);
    const int base = bs * DM + (rest & 15) * DH + j * 2;
    const float p = (float)pos[s];
    const float inv = __powf(10000.0f, (float)j * (-1.0f / 32.0f));
    float sn, cs;
    sincosf(p * inv, &sn, &cs);
    const uint32_t qp = *(const uint32_t*)(Q + base);
    const uint32_t kp = *(const uint32_t*)(K + base);
    const float qe = b2f((u16)qp), qo = b2f((u16)(qp >> 16));
    const float ke = b2f((u16)kp), ko = b2f((u16)(kp >> 16));
    const float oqe = (cs * qe - sn * qo) * 0.125f;
    const float oqo = (sn * qe + cs * qo) * 0.125f;
    const float oke = cs * ke - sn * ko;
    const float oko = sn * ke + cs * ko;
    *(uint32_t*)(Q + base) = (uint32_t)f2b(oqe) | ((uint32_t)f2b(oqo) << 16);
    *(uint32_t*)(K + base) = (uint32_t)f2b(oke) | ((uint32_t)f2b(oko) << 16);
  }
}

// ---------------- fused causal flash attention ----------------
// grid (S/64, B*H), 256 threads = 4 waves; wave w owns q rows [w*16, w*16+16)
__global__ __launch_bounds__(256) void attn_kernel(const u16* __restrict__ Qb,
                                                   const u16* __restrict__ Kb,
                                                   const u16* __restrict__ Vb,
                                                   u16* __restrict__ attb) {
  __shared__ u16 Qs[64 * 64], Ks[64 * 64], Vt[64 * 64], Ps[4][16 * 64];
  const int tid = threadIdx.x, lane = tid & 63, wid = tid >> 6;
  const int qt = blockIdx.x, bh = blockIdx.y;
  const int b = bh >> 4, h = bh & 15;
  const int q0 = qt * 64;
  const size_t base_bh = ((size_t)b * SEQ) * DM + h * DH;
  const int frow = lane & 15, fgrp = lane >> 4;

  // stage Q (swizzled via pre-swizzled global source)
  {
    int c = tid;
#pragma unroll
    for (int i = 0; i < 2; ++i, c += 256) {
      const int r = c >> 3, s8 = (c & 7) ^ (r & 7);
      gload_lds16(Qb + base_bh + (size_t)(q0 + r) * DM + s8 * 8,
                  (char*)Qs + wid * 1024 + i * 4096);
    }
  }
  __syncthreads();
  bf16x8 qf[2];
  {
    const int qrow = wid * 16 + frow;
#pragma unroll
    for (int ks = 0; ks < 2; ++ks) {
      const int byte = (qrow * 128 + ks * 64 + fgrp * 16) ^ ((qrow & 7) << 4);
      qf[ks] = *(const bf16x8*)((const char*)Qs + byte);
    }
  }

  float m_run[4] = {-1e30f, -1e30f, -1e30f, -1e30f};
  float l_run[4] = {0.f, 0.f, 0.f, 0.f};
  f32x4 accO[4] = {};

  for (int kt = 0; kt <= qt; ++kt) {
    const int kv0 = kt * 64;
    __syncthreads();
    {  // stage K
      int c = tid;
#pragma unroll
      for (int i = 0; i < 2; ++i, c += 256) {
        const int r = c >> 3, s8 = (c & 7) ^ (r & 7);
        gload_lds16(Kb + base_bh + (size_t)(kv0 + r) * DM + s8 * 8,
                    (char*)Ks + wid * 1024 + i * 4096);
      }
    }
    {  // stage V transposed (reg-staged)
      int c = tid;
#pragma unroll
      for (int i = 0; i < 2; ++i, c += 256) {
        const int r = c >> 3, c8 = c & 7;
        const ushort8v v = *(const ushort8v*)(Vb + base_bh + (size_t)(kv0 + r) * DM + c8 * 8);
#pragma unroll
        for (int j = 0; j < 8; ++j) {
          const int e = c8 * 8 + j;
          const int byte = (e * 128 + r * 2) ^ ((e & 7) << 4);
          *(u16*)((char*)Vt + byte) = v[j];
        }
      }
    }
    __syncthreads();

    // S = Q K^T  (16 q rows x 64 kv cols per wave)
    f32x4 sc[4] = {};
#pragma unroll
    for (int tc = 0; tc < 4; ++tc) {
      const int krow = tc * 16 + frow;
#pragma unroll
      for (int ks = 0; ks < 2; ++ks) {
        const int byte = (krow * 128 + ks * 64 + fgrp * 16) ^ ((krow & 7) << 4);
        const bf16x8 kf = *(const bf16x8*)((const char*)Ks + byte);
        sc[tc] = __builtin_amdgcn_mfma_f32_16x16x32_bf16(qf[ks], kf, sc[tc], 0, 0, 0);
      }
    }
    if (kt == qt) {  // causal mask on the diagonal tile
      const int rowl = wid * 16 + fgrp * 4;
#pragma unroll
      for (int tc = 0; tc < 4; ++tc) {
        const int coll = tc * 16 + frow;
#pragma unroll
        for (int r = 0; r < 4; ++r)
          if (coll > rowl + r) sc[tc][r] = -1e30f;
      }
    }
    // online softmax
    float rmax[4], rsum[4], scale[4];
#pragma unroll
    for (int r = 0; r < 4; ++r) {
      float v = fmaxf(fmaxf(sc[0][r], sc[1][r]), fmaxf(sc[2][r], sc[3][r]));
#pragma unroll
      for (int mxo = 1; mxo < 16; mxo <<= 1) v = fmaxf(v, __shfl_xor(v, mxo));
      rmax[r] = v;
    }
#pragma unroll
    for (int r = 0; r < 4; ++r) {
      const float mnew = fmaxf(m_run[r], rmax[r]);
      scale[r] = __expf(m_run[r] - mnew);
      m_run[r] = mnew;
      rsum[r] = 0.f;
    }
#pragma unroll
    for (int tc = 0; tc < 4; ++tc)
#pragma unroll
      for (int r = 0; r < 4; ++r) {
        const float p = __expf(sc[tc][r] - m_run[r]);
        sc[tc][r] = p;
        rsum[r] += p;
      }
#pragma unroll
    for (int r = 0; r < 4; ++r) {
#pragma unroll
      for (int mxo = 1; mxo < 16; mxo <<= 1) rsum[r] += __shfl_xor(rsum[r], mxo);
      l_run[r] = l_run[r] * scale[r] + rsum[r];
    }
#pragma unroll
    for (int t = 0; t < 4; ++t)
#pragma unroll
      for (int r = 0; r < 4; ++r) accO[t][r] *= scale[r];

    // P -> LDS (per-wave), then PV
    u16* Pw = Ps[wid];
#pragma unroll
    for (int tc = 0; tc < 4; ++tc)
#pragma unroll
      for (int r = 0; r < 4; ++r) {
        const int prow = fgrp * 4 + r, pcol = tc * 16 + frow;
        const int byte = (prow * 128 + pcol * 2) ^ ((prow & 7) << 4);
        *(u16*)((char*)Pw + byte) = f2b(sc[tc][r]);
      }
    bf16x8 pf[2];
#pragma unroll
    for (int ks = 0; ks < 2; ++ks) {
      const int byte = (frow * 128 + ks * 64 + fgrp * 16) ^ ((frow & 7) << 4);
      pf[ks] = *(const bf16x8*)((const char*)Pw + byte);
    }
#pragma unroll
    for (int te = 0; te < 4; ++te) {
      const int vrow = te * 16 + frow;
#pragma unroll
      for (int ks = 0; ks < 2; ++ks) {
        const int byte = (vrow * 128 + ks * 64 + fgrp * 16) ^ ((vrow & 7) << 4);
        const bf16x8 vf = *(const bf16x8*)((const char*)Vt + byte);
        accO[te] = __builtin_amdgcn_mfma_f32_16x16x32_bf16(pf[ks], vf, accO[te], 0, 0, 0);
      }
    }
  }

  // epilogue: O /= l, write att (b, s, h, e) as bf16
#pragma unroll
  for (int te = 0; te < 4; ++te)
#pragma unroll
    for (int r = 0; r < 4; ++r) {
      const float o = accO[te][r] / l_run[r];
      const int row = q0 + wid * 16 + fgrp * 4 + r;
      const int col = te * 16 + frow;
      attb[base_bh + (size_t)row * DM + col] = f2b(o);
    }
}

extern "C" void kernel_launch(void* const* d_in, const int* in_sizes, int n_in,
                              void* d_out, int out_size, void* d_ws, size_t ws_size,
                              hipStream_t stream) {
  const float* x  = (const float*)d_in[0];
  const float* wq = (const float*)d_in[1];
  const float* wk = (const float*)d_in[2];
  const float* wv = (const float*)d_in[3];
  const float* wo = (const float*)d_in[4];
  const int* pos  = (const int*)d_in[5];
  float* out = (float*)d_out;
  (void)in_sizes; (void)n_in; (void)out_size; (void)ws_size;

  char* ws = (char*)d_ws;
  const size_t MB = 1024 * 1024;
  u16* xb   = (u16*)(ws);
  u16* wqb  = (u16*)(ws + 8 * MB);
  u16* wkb  = (u16*)(ws + 10 * MB);
  u16* wvb  = (u16*)(ws + 12 * MB);
  u16* wob  = (u16*)(ws + 14 * MB);
  u16* Qb   = (u16*)(ws + 16 * MB);
  u16* Kb   = (u16*)(ws + 24 * MB);
  u16* Vb   = (u16*)(ws + 32 * MB);
  u16* attb = (u16*)(ws + 40 * MB);

  cast_kernel<<<1024, 256, 0, stream>>>(x,  xb,  (BATCH * SEQ * DM) / 4);
  cast_kernel<<<512, 256, 0, stream>>>(wq, wqb, (DM * DM) / 4);
  cast_kernel<<<512, 256, 0, stream>>>(wk, wkb, (DM * DM) / 4);
  cast_kernel<<<512, 256, 0, stream>>>(wv, wvb, (DM * DM) / 4);
  cast_kernel<<<512, 256, 0, stream>>>(wo, wob, (DM * DM) / 4);

  gemm_qkv<<<dim3(8, 32, 3), 256, 0, stream>>>(xb, wqb, wkb, wvb, Qb, Kb, Vb);
  rope_kernel<<<2048, 256, 0, stream>>>(Qb, Kb, pos, BATCH * SEQ * NH * 32);
  attn_kernel<<<dim3(SEQ / 64, BATCH * NH), 256, 0, stream>>>(Qb, Kb, Vb, attb);
  gemm_o<<<dim3(8, 32, 1), 256, 0, stream>>>(attb, wob, out);
}

// Round 2
// 224.922 us; speedup vs baseline: 1.1435x; 1.1435x over previous
//
#include <hip/hip_runtime.h>
#include <hip/hip_bf16.h>
#include <cstdint>
#include <cstddef>

#define DEV static __device__ __forceinline__

typedef __bf16 bf16x8 __attribute__((ext_vector_type(8)));
typedef float f32x4 __attribute__((ext_vector_type(4)));
typedef unsigned short u16;

static constexpr int BATCH = 2, SEQ = 2048, DM = 1024, NH = 16, DH = 64;
static constexpr int Kdim = 1024;
static constexpr int BS = BATCH * SEQ;  // 4096

DEV u16 f2b(float f) {  // f32 -> bf16 RNE
  uint32_t u = __builtin_bit_cast(uint32_t, f);
  u += 0x7FFFu + ((u >> 16) & 1u);
  return (u16)(u >> 16);
}
DEV float b2f(u16 v) { return __builtin_bit_cast(float, (uint32_t)v << 16); }

DEV void gload_lds16(const void* g, void* l) {
  __builtin_amdgcn_global_load_lds((const __attribute__((address_space(1))) void*)g,
                                   (__attribute__((address_space(3))) void*)l, 16, 0, 0);
}

// ---------------- cast f32 -> bf16 (vectorized x4) ----------------
__global__ __launch_bounds__(256) void cast_kernel(const float* __restrict__ src,
                                                   u16* __restrict__ dst, int n4) {
  int i = blockIdx.x * blockDim.x + threadIdx.x;
  const int stride = gridDim.x * blockDim.x;
  for (; i < n4; i += stride) {
    float4 v = ((const float4*)src)[i];
    ushort4 o;
    o.x = f2b(v.x); o.y = f2b(v.y); o.z = f2b(v.z); o.w = f2b(v.w);
    ((ushort4*)dst)[i] = o;
  }
}

// ---------------- GEMM: C[M, N] = A[M,1024] * B[N,1024]^T ----------------
// 128x128 tile, BK=32, 4 waves (2x2), 16x16x32 bf16 MFMA, global_load_lds staging.
// grid = (N/128, M/128); ldC = N.
template <bool OUTF32>
DEV void gemm_core(const u16* __restrict__ A, const u16* __restrict__ Bm,
                   void* __restrict__ Cout, int ldC) {
  __shared__ u16 As[128 * 32], Bs[128 * 32];
  const int tid = threadIdx.x;
  const int lane = tid & 63, wid = tid >> 6;
  const int m0 = blockIdx.y * 128, n0 = blockIdx.x * 128;
  const int wr = (wid >> 1) * 64, wc = (wid & 1) * 64;
  const int frow = lane & 15, fgrp = lane >> 4;
  f32x4 acc[4][4] = {};

  const int c0 = tid, c1 = tid + 256;
  const int r0 = c0 >> 2, s80 = (c0 & 3) ^ (r0 & 3);
  const int r1 = c1 >> 2, s81 = (c1 & 3) ^ (r1 & 3);
  const size_t gA0 = (size_t)(m0 + r0) * Kdim + s80 * 8;
  const size_t gA1 = (size_t)(m0 + r1) * Kdim + s81 * 8;
  const size_t gB0 = (size_t)(n0 + r0) * Kdim + s80 * 8;
  const size_t gB1 = (size_t)(n0 + r1) * Kdim + s81 * 8;
  u16* ldsA0 = As + wid * 512;        u16* ldsA1 = As + wid * 512 + 2048;
  u16* ldsB0 = Bs + wid * 512;        u16* ldsB1 = Bs + wid * 512 + 2048;

  for (int kt = 0; kt < Kdim / 32; ++kt) {
    const int k0 = kt * 32;
    __syncthreads();
    gload_lds16(A + gA0 + k0, ldsA0);
    gload_lds16(A + gA1 + k0, ldsA1);
    gload_lds16(Bm + gB0 + k0, ldsB0);
    gload_lds16(Bm + gB1 + k0, ldsB1);
    __syncthreads();
    bf16x8 af[4], bfr[4];
#pragma unroll
    for (int i = 0; i < 4; ++i) {
      const int ra = wr + i * 16 + frow;
      const int rb = wc + i * 16 + frow;
      af[i]  = *(const bf16x8*)((const char*)As + ra * 64 + ((fgrp ^ (ra & 3)) * 16));
      bfr[i] = *(const bf16x8*)((const char*)Bs + rb * 64 + ((fgrp ^ (rb & 3)) * 16));
    }
#pragma unroll
    for (int mi = 0; mi < 4; ++mi)
#pragma unroll
      for (int ni = 0; ni < 4; ++ni)
        acc[mi][ni] = __builtin_amdgcn_mfma_f32_16x16x32_bf16(af[mi], bfr[ni], acc[mi][ni], 0, 0, 0);
  }
  const int colb = n0 + wc + frow;
  const int rowb = m0 + wr + fgrp * 4;
#pragma unroll
  for (int mi = 0; mi < 4; ++mi)
#pragma unroll
    for (int ni = 0; ni < 4; ++ni)
#pragma unroll
      for (int r = 0; r < 4; ++r) {
        const int row = rowb + mi * 16 + r;
        const int col = colb + ni * 16;
        const float v = acc[mi][ni][r];
        if (OUTF32) ((float*)Cout)[(size_t)row * ldC + col] = v;
        else        ((u16*)Cout)[(size_t)row * ldC + col] = f2b(v);
      }
}

__global__ __launch_bounds__(256) void gemm_qk(const u16* __restrict__ xb,
    const u16* __restrict__ wq, const u16* __restrict__ wk,
    u16* __restrict__ Qb, u16* __restrict__ Kb) {
  const u16* W = (blockIdx.z == 0) ? wq : wk;
  u16* O = (blockIdx.z == 0) ? Qb : Kb;
  gemm_core<false>(xb, W, O, DM);
}

// V^T[e_glob, b*S+s] = sum_d Wv[e_glob,d] * x[b*S+s,d]  -> C = Wv * X^T, M=1024, N=4096
__global__ __launch_bounds__(256) void gemm_vt(const u16* __restrict__ wv,
                                               const u16* __restrict__ xb,
                                               u16* __restrict__ Vtb) {
  gemm_core<false>(wv, xb, Vtb, BS);
}

__global__ __launch_bounds__(256) void gemm_o(const u16* __restrict__ attb,
                                              const u16* __restrict__ wob,
                                              float* __restrict__ out) {
  gemm_core<true>(attb, wob, out, DM);
}

// ---------------- RoPE on Q and K (in place, bf16), folds 1/8 scale into Q ----------------
__global__ __launch_bounds__(256) void rope_kernel(u16* __restrict__ Q, u16* __restrict__ K,
                                                   const int* __restrict__ pos, int npairs) {
  int i = blockIdx.x * blockDim.x + threadIdx.x;
  const int stride = gridDim.x * blockDim.x;
  for (; i < npairs; i += stride) {
    const int j = i & 31;
    const int rest = i >> 5;                    // (b*S+s)*16 + h
    const int bs = rest >> 4;                   // b*S+s
    const int s = bs & (SEQ - 1);
    const int base = bs * DM + (rest & 15) * DH + j * 2;
    const float p = (float)pos[s];
    const float inv = __powf(10000.0f, (float)j * (-1.0f / 32.0f));
    float sn, cs;
    sincosf(p * inv, &sn, &cs);
    const uint32_t qp = *(const uint32_t*)(Q + base);
    const uint32_t kp = *(const uint32_t*)(K + base);
    const float qe = b2f((u16)qp), qo = b2f((u16)(qp >> 16));
    const float ke = b2f((u16)kp), ko = b2f((u16)(kp >> 16));
    const float oqe = (cs * qe - sn * qo) * 0.125f;
    const float oqo = (sn * qe + cs * qo) * 0.125f;
    const float oke = cs * ke - sn * ko;
    const float oko = sn * ke + cs * ko;
    *(uint32_t*)(Q + base) = (uint32_t)f2b(oqe) | ((uint32_t)f2b(oqo) << 16);
    *(uint32_t*)(K + base) = (uint32_t)f2b(oke) | ((uint32_t)f2b(oko) << 16);
  }
}

// ---------------- fused causal flash attention ----------------
// grid (S/64, B*H), 256 threads = 4 waves; wave w owns q rows [w*16, w*16+16)
// Heavy-first: qt = 31 - blockIdx.x. K and V^T double-buffered (2-phase pipeline).
__global__ __launch_bounds__(256) void attn_kernel(const u16* __restrict__ Qb,
                                                   const u16* __restrict__ Kb,
                                                   const u16* __restrict__ Vtb,
                                                   u16* __restrict__ attb) {
  __shared__ u16 Qs[64 * 64], Ks[2][64 * 64], Vt[2][64 * 64], Ps[4][16 * 64];
  const int tid = threadIdx.x, lane = tid & 63, wid = tid >> 6;
  const int qt = (int)(gridDim.x - 1 - blockIdx.x);   // heavy blocks first
  const int bh = blockIdx.y;
  const int b = bh >> 4, h = bh & 15;
  const int q0 = qt * 64;
  const size_t base_bh = ((size_t)b * SEQ) * DM + h * DH;
  const int frow = lane & 15, fgrp = lane >> 4;

  // per-thread staging coords: chunk c -> row r = c>>3, swizzled col chunk s8
  const int c0 = tid, c1 = tid + 256;
  const int r0 = c0 >> 3, s80 = (c0 & 7) ^ (r0 & 7);
  const int r1 = c1 >> 3, s81 = (c1 & 7) ^ (r1 & 7);

  // source bases (kv offset added per iteration)
  const u16* Ksrc0 = Kb + base_bh + (size_t)r0 * DM + s80 * 8;
  const u16* Ksrc1 = Kb + base_bh + (size_t)r1 * DM + s81 * 8;
  const u16* Vsrc0 = Vtb + (size_t)(h * DH + r0) * BS + (size_t)b * SEQ + s80 * 8;
  const u16* Vsrc1 = Vtb + (size_t)(h * DH + r1) * BS + (size_t)b * SEQ + s81 * 8;

  // prologue: stage Q + (K, V^T) tile 0
  gload_lds16(Qb + base_bh + (size_t)(q0 + r0) * DM + s80 * 8, (char*)Qs + wid * 1024);
  gload_lds16(Qb + base_bh + (size_t)(q0 + r1) * DM + s81 * 8, (char*)Qs + wid * 1024 + 4096);
  gload_lds16(Ksrc0, (char*)Ks[0] + wid * 1024);
  gload_lds16(Ksrc1, (char*)Ks[0] + wid * 1024 + 4096);
  gload_lds16(Vsrc0, (char*)Vt[0] + wid * 1024);
  gload_lds16(Vsrc1, (char*)Vt[0] + wid * 1024 + 4096);
  __syncthreads();

  bf16x8 qf[2];
  {
    const int qrow = wid * 16 + frow;
#pragma unroll
    for (int ks = 0; ks < 2; ++ks) {
      const int byte = (qrow * 128 + ks * 64 + fgrp * 16) ^ ((qrow & 7) << 4);
      qf[ks] = *(const bf16x8*)((const char*)Qs + byte);
    }
  }

  float m_run[4] = {-1e30f, -1e30f, -1e30f, -1e30f};
  float l_run[4] = {0.f, 0.f, 0.f, 0.f};
  f32x4 accO[4] = {};
  int cur = 0;

  for (int kt = 0; kt <= qt; ++kt) {
    // issue next tile's staging first (overlaps with compute below)
    if (kt < qt) {
      const size_t kvn = (size_t)(kt + 1) * 64;
      gload_lds16(Ksrc0 + kvn * DM, (char*)Ks[cur ^ 1] + wid * 1024);
      gload_lds16(Ksrc1 + kvn * DM, (char*)Ks[cur ^ 1] + wid * 1024 + 4096);
      gload_lds16(Vsrc0 + kvn, (char*)Vt[cur ^ 1] + wid * 1024);
      gload_lds16(Vsrc1 + kvn, (char*)Vt[cur ^ 1] + wid * 1024 + 4096);
    }

    // S = Q K^T  (16 q rows x 64 kv cols per wave)
    f32x4 sc[4] = {};
#pragma unroll
    for (int tc = 0; tc < 4; ++tc) {
      const int krow = tc * 16 + frow;
#pragma unroll
      for (int ks = 0; ks < 2; ++ks) {
        const int byte = (krow * 128 + ks * 64 + fgrp * 16) ^ ((krow & 7) << 4);
        const bf16x8 kf = *(const bf16x8*)((const char*)Ks[cur] + byte);
        sc[tc] = __builtin_amdgcn_mfma_f32_16x16x32_bf16(qf[ks], kf, sc[tc], 0, 0, 0);
      }
    }
    if (kt == qt) {  // causal mask on the diagonal tile
      const int rowl = wid * 16 + fgrp * 4;
#pragma unroll
      for (int tc = 0; tc < 4; ++tc) {
        const int coll = tc * 16 + frow;
#pragma unroll
        for (int r = 0; r < 4; ++r)
          if (coll > rowl + r) sc[tc][r] = -1e30f;
      }
    }
    // online softmax
    float rmax[4], rsum[4], scale[4];
#pragma unroll
    for (int r = 0; r < 4; ++r) {
      float v = fmaxf(fmaxf(sc[0][r], sc[1][r]), fmaxf(sc[2][r], sc[3][r]));
#pragma unroll
      for (int mxo = 1; mxo < 16; mxo <<= 1) v = fmaxf(v, __shfl_xor(v, mxo));
      rmax[r] = v;
    }
#pragma unroll
    for (int r = 0; r < 4; ++r) {
      const float mnew = fmaxf(m_run[r], rmax[r]);
      scale[r] = __expf(m_run[r] - mnew);
      m_run[r] = mnew;
      rsum[r] = 0.f;
    }
#pragma unroll
    for (int tc = 0; tc < 4; ++tc)
#pragma unroll
      for (int r = 0; r < 4; ++r) {
        const float p = __expf(sc[tc][r] - m_run[r]);
        sc[tc][r] = p;
        rsum[r] += p;
      }
#pragma unroll
    for (int r = 0; r < 4; ++r) {
#pragma unroll
      for (int mxo = 1; mxo < 16; mxo <<= 1) rsum[r] += __shfl_xor(rsum[r], mxo);
      l_run[r] = l_run[r] * scale[r] + rsum[r];
    }
#pragma unroll
    for (int t = 0; t < 4; ++t)
#pragma unroll
      for (int r = 0; r < 4; ++r) accO[t][r] *= scale[r];

    // P -> LDS (per-wave private region), then PV
    u16* Pw = Ps[wid];
#pragma unroll
    for (int tc = 0; tc < 4; ++tc)
#pragma unroll
      for (int r = 0; r < 4; ++r) {
        const int prow = fgrp * 4 + r, pcol = tc * 16 + frow;
        const int byte = (prow * 128 + pcol * 2) ^ ((prow & 7) << 4);
        *(u16*)((char*)Pw + byte) = f2b(sc[tc][r]);
      }
    bf16x8 pf[2];
#pragma unroll
    for (int ks = 0; ks < 2; ++ks) {
      const int byte = (frow * 128 + ks * 64 + fgrp * 16) ^ ((frow & 7) << 4);
      pf[ks] = *(const bf16x8*)((const char*)Pw + byte);
    }
#pragma unroll
    for (int te = 0; te < 4; ++te) {
      const int vrow = te * 16 + frow;   // V^T row = head-dim e
#pragma unroll
      for (int ks = 0; ks < 2; ++ks) {
        const int byte = (vrow * 128 + ks * 64 + fgrp * 16) ^ ((vrow & 7) << 4);
        const bf16x8 vf = *(const bf16x8*)((const char*)Vt[cur] + byte);
        accO[te] = __builtin_amdgcn_mfma_f32_16x16x32_bf16(pf[ks], vf, accO[te], 0, 0, 0);
      }
    }
    __syncthreads();   // drains vmcnt for next tile's staging; protects buffer swap
    cur ^= 1;
  }

  // epilogue: O /= l, write att (b, s, h, e) as bf16
#pragma unroll
  for (int te = 0; te < 4; ++te)
#pragma unroll
    for (int r = 0; r < 4; ++r) {
      const float o = accO[te][r] / l_run[r];
      const int row = q0 + wid * 16 + fgrp * 4 + r;
      const int col = te * 16 + frow;
      attb[base_bh + (size_t)row * DM + col] = f2b(o);
    }
}

extern "C" void kernel_launch(void* const* d_in, const int* in_sizes, int n_in,
                              void* d_out, int out_size, void* d_ws, size_t ws_size,
                              hipStream_t stream) {
  const float* x  = (const float*)d_in[0];
  const float* wq = (const float*)d_in[1];
  const float* wk = (const float*)d_in[2];
  const float* wv = (const float*)d_in[3];
  const float* wo = (const float*)d_in[4];
  const int* pos  = (const int*)d_in[5];
  float* out = (float*)d_out;
  (void)in_sizes; (void)n_in; (void)out_size; (void)ws_size;

  char* ws = (char*)d_ws;
  const size_t MB = 1024 * 1024;
  u16* xb   = (u16*)(ws);
  u16* wqb  = (u16*)(ws + 8 * MB);
  u16* wkb  = (u16*)(ws + 10 * MB);
  u16* wvb  = (u16*)(ws + 12 * MB);
  u16* wob  = (u16*)(ws + 14 * MB);
  u16* Qb   = (u16*)(ws + 16 * MB);
  u16* Kb   = (u16*)(ws + 24 * MB);
  u16* Vtb  = (u16*)(ws + 32 * MB);  // V^T: [1024][4096]
  u16* attb = (u16*)(ws + 40 * MB);

  cast_kernel<<<1024, 256, 0, stream>>>(x,  xb,  (BATCH * SEQ * DM) / 4);
  cast_kernel<<<512, 256, 0, stream>>>(wq, wqb, (DM * DM) / 4);
  cast_kernel<<<512, 256, 0, stream>>>(wk, wkb, (DM * DM) / 4);
  cast_kernel<<<512, 256, 0, stream>>>(wv, wvb, (DM * DM) / 4);
  cast_kernel<<<512, 256, 0, stream>>>(wo, wob, (DM * DM) / 4);

  gemm_qk<<<dim3(8, 32, 2), 256, 0, stream>>>(xb, wqb, wkb, Qb, Kb);
  gemm_vt<<<dim3(32, 8, 1), 256, 0, stream>>>(wvb, xb ? xb : xb, Vtb);
  rope_kernel<<<2048, 256, 0, stream>>>(Qb, Kb, pos, BATCH * SEQ * NH * 32);
  attn_kernel<<<dim3(SEQ / 64, BATCH * NH), 256, 0, stream>>>(Qb, Kb, Vtb, attb);
  gemm_o<<<dim3(8, 32, 1), 256, 0, stream>>>(attb, wob, out);
}

// Round 4
// 133.860 us; speedup vs baseline: 1.9213x; 1.6803x over previous
//
#include <hip/hip_runtime.h>
#include <hip/hip_bf16.h>
#include <cstdint>
#include <cstddef>

#define DEV static __device__ __forceinline__

typedef __bf16 bf16x8 __attribute__((ext_vector_type(8)));
typedef float f32x4 __attribute__((ext_vector_type(4)));
typedef unsigned short u16;

static constexpr int BATCH = 2, SEQ = 2048, DM = 1024, NH = 16, DH = 64;
static constexpr int Kdim = 1024;
static constexpr int BS = BATCH * SEQ;  // 4096

DEV u16 f2b(float f) {  // f32 -> bf16 RNE
  uint32_t u = __builtin_bit_cast(uint32_t, f);
  u += 0x7FFFu + ((u >> 16) & 1u);
  return (u16)(u >> 16);
}
DEV float b2f(u16 v) { return __builtin_bit_cast(float, (uint32_t)v << 16); }

DEV void gload_lds16(const void* g, void* l) {
  __builtin_amdgcn_global_load_lds((const __attribute__((address_space(1))) void*)g,
                                   (__attribute__((address_space(3))) void*)l, 16, 0, 0);
}

// ---------------- fused cast f32 -> bf16 (x + 4 weights, one launch) ----------------
__global__ __launch_bounds__(256) void cast_all(const float* __restrict__ x,
    const float* __restrict__ wq, const float* __restrict__ wk,
    const float* __restrict__ wv, const float* __restrict__ wo,
    u16* __restrict__ xb, u16* __restrict__ wqb, u16* __restrict__ wkb,
    u16* __restrict__ wvb, u16* __restrict__ wob) {
  const int NX = (BATCH * SEQ * DM) / 4;  // 2097152
  const int NW = (DM * DM) / 4;           // 262144 = 1<<18
  int i = blockIdx.x * blockDim.x + threadIdx.x;
  const int stride = gridDim.x * blockDim.x;
  for (; i < NX + 4 * NW; i += stride) {
    const float* src; u16* dst; int off;
    if (i < NX) { src = x; dst = xb; off = i; }
    else {
      const int j = i - NX, seg = j >> 18;
      off = j & (NW - 1);
      src = seg == 0 ? wq : seg == 1 ? wk : seg == 2 ? wv : wo;
      dst = seg == 0 ? wqb : seg == 1 ? wkb : seg == 2 ? wvb : wob;
    }
    float4 v = ((const float4*)src)[off];
    ushort4 o;
    o.x = f2b(v.x); o.y = f2b(v.y); o.z = f2b(v.z); o.w = f2b(v.w);
    ((ushort4*)dst)[off] = o;
  }
}

// ---------------- GEMM core: C[m0.., n0..] = A[M,1024] * B[N,1024]^T ----------------
// 128x128 tile, BK=32, 4 waves (2x2), 16x16x32 bf16 MFMA, global_load_lds staging.
template <bool OUTF32>
DEV void gemm_core(const u16* __restrict__ A, const u16* __restrict__ Bm,
                   void* __restrict__ Cout, int ldC, int m0, int n0) {
  __shared__ u16 As[128 * 32], Bs[128 * 32];
  const int tid = threadIdx.x;
  const int lane = tid & 63, wid = tid >> 6;
  const int wr = (wid >> 1) * 64, wc = (wid & 1) * 64;
  const int frow = lane & 15, fgrp = lane >> 4;
  f32x4 acc[4][4] = {};

  const int c0 = tid, c1 = tid + 256;
  const int r0 = c0 >> 2, s80 = (c0 & 3) ^ (r0 & 3);
  const int r1 = c1 >> 2, s81 = (c1 & 3) ^ (r1 & 3);
  const size_t gA0 = (size_t)(m0 + r0) * Kdim + s80 * 8;
  const size_t gA1 = (size_t)(m0 + r1) * Kdim + s81 * 8;
  const size_t gB0 = (size_t)(n0 + r0) * Kdim + s80 * 8;
  const size_t gB1 = (size_t)(n0 + r1) * Kdim + s81 * 8;
  u16* ldsA0 = As + wid * 512;        u16* ldsA1 = As + wid * 512 + 2048;
  u16* ldsB0 = Bs + wid * 512;        u16* ldsB1 = Bs + wid * 512 + 2048;

  for (int kt = 0; kt < Kdim / 32; ++kt) {
    const int k0 = kt * 32;
    __syncthreads();
    gload_lds16(A + gA0 + k0, ldsA0);
    gload_lds16(A + gA1 + k0, ldsA1);
    gload_lds16(Bm + gB0 + k0, ldsB0);
    gload_lds16(Bm + gB1 + k0, ldsB1);
    __syncthreads();
    bf16x8 af[4], bfr[4];
#pragma unroll
    for (int i = 0; i < 4; ++i) {
      const int ra = wr + i * 16 + frow;
      const int rb = wc + i * 16 + frow;
      af[i]  = *(const bf16x8*)((const char*)As + ra * 64 + ((fgrp ^ (ra & 3)) * 16));
      bfr[i] = *(const bf16x8*)((const char*)Bs + rb * 64 + ((fgrp ^ (rb & 3)) * 16));
    }
#pragma unroll
    for (int mi = 0; mi < 4; ++mi)
#pragma unroll
      for (int ni = 0; ni < 4; ++ni)
        acc[mi][ni] = __builtin_amdgcn_mfma_f32_16x16x32_bf16(af[mi], bfr[ni], acc[mi][ni], 0, 0, 0);
  }
  const int colb = n0 + wc + frow;
  const int rowb = m0 + wr + fgrp * 4;
#pragma unroll
  for (int mi = 0; mi < 4; ++mi)
#pragma unroll
    for (int ni = 0; ni < 4; ++ni)
#pragma unroll
      for (int r = 0; r < 4; ++r) {
        const int row = rowb + mi * 16 + r;
        const int col = colb + ni * 16;
        const float v = acc[mi][ni][r];
        if (OUTF32) ((float*)Cout)[(size_t)row * ldC + col] = v;
        else        ((u16*)Cout)[(size_t)row * ldC + col] = f2b(v);
      }
}

// z=0: Q = X*Wq^T (4096x1024); z=1: K = X*Wk^T; z=2: V^T = Wv*X^T (1024x4096)
__global__ __launch_bounds__(256) void gemm_qkvt(const u16* __restrict__ xb,
    const u16* __restrict__ wq, const u16* __restrict__ wk, const u16* __restrict__ wv,
    u16* __restrict__ Qb, u16* __restrict__ Kb, u16* __restrict__ Vtb) {
  const int i = blockIdx.x, z = blockIdx.z;
  if (z == 0)      gemm_core<false>(xb, wq, Qb, DM, (i >> 3) * 128, (i & 7) * 128);
  else if (z == 1) gemm_core<false>(xb, wk, Kb, DM, (i >> 3) * 128, (i & 7) * 128);
  else             gemm_core<false>(wv, xb, Vtb, BS, (i >> 5) * 128, (i & 31) * 128);
}

__global__ __launch_bounds__(256) void gemm_o(const u16* __restrict__ attb,
                                              const u16* __restrict__ wob,
                                              float* __restrict__ out) {
  gemm_core<true>(attb, wob, out, DM, blockIdx.y * 128, blockIdx.x * 128);
}

// ---------------- RoPE on Q and K (in place, bf16), folds 1/8 scale into Q ----------------
__global__ __launch_bounds__(256) void rope_kernel(u16* __restrict__ Q, u16* __restrict__ K,
                                                   const int* __restrict__ pos, int npairs) {
  int i = blockIdx.x * blockDim.x + threadIdx.x;
  const int stride = gridDim.x * blockDim.x;
  for (; i < npairs; i += stride) {
    const int j = i & 31;
    const int rest = i >> 5;                    // (b*S+s)*16 + h
    const int bs = rest >> 4;                   // b*S+s
    const int s = bs & (SEQ - 1);
    const int base = bs * DM + (rest & 15) * DH + j * 2;
    const float p = (float)pos[s];
    // theta^(-2k/dk) = 2^(-j*log2(1e4)/32)
    const float inv = exp2f((float)j * -0.4152410118609203f);
    float sn, cs;
    sincosf(p * inv, &sn, &cs);
    const uint32_t qp = *(const uint32_t*)(Q + base);
    const uint32_t kp = *(const uint32_t*)(K + base);
    const float qe = b2f((u16)qp), qo = b2f((u16)(qp >> 16));
    const float ke = b2f((u16)kp), ko = b2f((u16)(kp >> 16));
    const float oqe = (cs * qe - sn * qo) * 0.125f;
    const float oqo = (sn * qe + cs * qo) * 0.125f;
    const float oke = cs * ke - sn * ko;
    const float oko = sn * ke + cs * ko;
    *(uint32_t*)(Q + base) = (uint32_t)f2b(oqe) | ((uint32_t)f2b(oqo) << 16);
    *(uint32_t*)(K + base) = (uint32_t)f2b(oke) | ((uint32_t)f2b(oko) << 16);
  }
}

// ---------------- fused causal flash attention ----------------
// grid (16, 32): block x handles q-tiles {31-x, x} (33 KV iters total — balanced).
// 256 threads = 4 waves; wave w owns q rows [w*16, w*16+16) of the 64-row tile.
// Swapped QK^T: sc = mfma(K, Q) puts S[q=frow][k=fgrp*4+r+16tc] lane-local
// -> row softmax is 15 VALU + 2 shuffles; P written as 4x ds_write_b64.
__global__ __launch_bounds__(256) void attn_kernel(const u16* __restrict__ Qb,
                                                   const u16* __restrict__ Kb,
                                                   const u16* __restrict__ Vtb,
                                                   u16* __restrict__ attb) {
  __shared__ u16 Qs[64 * 64], Ks[2][64 * 64], Vt[2][64 * 64], Ps[4][16 * 64];
  const int tid = threadIdx.x, lane = tid & 63, wid = tid >> 6;
  const int bh = blockIdx.y;
  const int b = bh >> 4, h = bh & 15;
  const size_t base_bh = ((size_t)b * SEQ) * DM + h * DH;
  const int frow = lane & 15, fgrp = lane >> 4;

  // staging coords: chunk c -> row r=c>>3, swizzled col chunk s8
  const int c0 = tid, c1 = tid + 256;
  const int r0 = c0 >> 3, s80 = (c0 & 7) ^ (r0 & 7);
  const int r1 = c1 >> 3, s81 = (c1 & 7) ^ (r1 & 7);

  const u16* Ksrc0 = Kb + base_bh + (size_t)r0 * DM + s80 * 8;
  const u16* Ksrc1 = Kb + base_bh + (size_t)r1 * DM + s81 * 8;
  const u16* Vsrc0 = Vtb + (size_t)(h * DH + r0) * BS + (size_t)b * SEQ + s80 * 8;
  const u16* Vsrc1 = Vtb + (size_t)(h * DH + r1) * BS + (size_t)b * SEQ + s81 * 8;

  const int qrow = wid * 16 + frow;  // local q row this lane reduces

#pragma unroll 1
  for (int phase = 0; phase < 2; ++phase) {
    const int qt = phase ? (int)blockIdx.x : 31 - (int)blockIdx.x;
    const int q0 = qt * 64;

    // prologue: stage Q + (K, V^T) tile 0   (safe: all LDS readers passed last barrier)
    gload_lds16(Qb + base_bh + (size_t)(q0 + r0) * DM + s80 * 8, (char*)Qs + wid * 1024);
    gload_lds16(Qb + base_bh + (size_t)(q0 + r1) * DM + s81 * 8, (char*)Qs + wid * 1024 + 4096);
    gload_lds16(Ksrc0, (char*)Ks[0] + wid * 1024);
    gload_lds16(Ksrc1, (char*)Ks[0] + wid * 1024 + 4096);
    gload_lds16(Vsrc0, (char*)Vt[0] + wid * 1024);
    gload_lds16(Vsrc1, (char*)Vt[0] + wid * 1024 + 4096);
    __syncthreads();

    bf16x8 qf[2];
#pragma unroll
    for (int ks = 0; ks < 2; ++ks) {
      const int byte = (qrow * 128 + ks * 64 + fgrp * 16) ^ ((qrow & 7) << 4);
      qf[ks] = *(const bf16x8*)((const char*)Qs + byte);
    }

    float m_sc = -1e30f, l_sc = 0.f;
    f32x4 accO[4] = {};
    int cur = 0;

    for (int kt = 0; kt <= qt; ++kt) {
      if (kt < qt) {  // prefetch next tile (overlaps compute; drained by end barrier)
        const size_t kvn = (size_t)(kt + 1) * 64;
        gload_lds16(Ksrc0 + kvn * DM, (char*)Ks[cur ^ 1] + wid * 1024);
        gload_lds16(Ksrc1 + kvn * DM, (char*)Ks[cur ^ 1] + wid * 1024 + 4096);
        gload_lds16(Vsrc0 + kvn, (char*)Vt[cur ^ 1] + wid * 1024);
        gload_lds16(Vsrc1 + kvn, (char*)Vt[cur ^ 1] + wid * 1024 + 4096);
      }

      // S^T tiles: sc[tc][r] = S[q=frow][k = tc*16 + fgrp*4 + r]
      f32x4 sc[4] = {};
#pragma unroll
      for (int tc = 0; tc < 4; ++tc) {
        const int krow = tc * 16 + frow;
#pragma unroll
        for (int ks = 0; ks < 2; ++ks) {
          const int byte = (krow * 128 + ks * 64 + fgrp * 16) ^ ((krow & 7) << 4);
          const bf16x8 kf = *(const bf16x8*)((const char*)Ks[cur] + byte);
          sc[tc] = __builtin_amdgcn_mfma_f32_16x16x32_bf16(kf, qf[ks], sc[tc], 0, 0, 0);
        }
      }
      if (kt == qt) {  // causal mask on diagonal tile (local coords, kv0 == q0)
#pragma unroll
        for (int tc = 0; tc < 4; ++tc)
#pragma unroll
          for (int r = 0; r < 4; ++r)
            if (tc * 16 + fgrp * 4 + r > qrow) sc[tc][r] = -1e30f;
      }

      // online softmax: lane-local 16 + cross-fgrp (lanes ^16, ^32 share frow)
      float vmax = fmaxf(fmaxf(sc[0][0], sc[0][1]), fmaxf(sc[0][2], sc[0][3]));
#pragma unroll
      for (int tc = 1; tc < 4; ++tc)
        vmax = fmaxf(vmax, fmaxf(fmaxf(sc[tc][0], sc[tc][1]), fmaxf(sc[tc][2], sc[tc][3])));
      vmax = fmaxf(vmax, __shfl_xor(vmax, 16));
      vmax = fmaxf(vmax, __shfl_xor(vmax, 32));
      const float mnew = fmaxf(m_sc, vmax);
      const float sc_scale = __expf(m_sc - mnew);
      m_sc = mnew;
      float rsum = 0.f;
#pragma unroll
      for (int tc = 0; tc < 4; ++tc)
#pragma unroll
        for (int r = 0; r < 4; ++r) {
          const float p = __expf(sc[tc][r] - mnew);
          sc[tc][r] = p;
          rsum += p;
        }
      rsum += __shfl_xor(rsum, 16);
      rsum += __shfl_xor(rsum, 32);
      l_sc = l_sc * sc_scale + rsum;

      // rescale O (accO rows are q = fgrp*4 + r; fetch that row's scale)
#pragma unroll
      for (int r = 0; r < 4; ++r) {
        const float s = __shfl(sc_scale, fgrp * 4 + r, 64);
#pragma unroll
        for (int te = 0; te < 4; ++te) accO[te][r] *= s;
      }

      // P -> LDS: 4x b64 (k-contiguous per lane), 2-way bank alias (free)
      u16* Pw = Ps[wid];
#pragma unroll
      for (int tc = 0; tc < 4; ++tc) {
        const uint32_t lo = (uint32_t)f2b(sc[tc][0]) | ((uint32_t)f2b(sc[tc][1]) << 16);
        const uint32_t hi = (uint32_t)f2b(sc[tc][2]) | ((uint32_t)f2b(sc[tc][3]) << 16);
        const int byte = (frow * 128 + tc * 32 + fgrp * 8) ^ ((frow & 7) << 4);
        *(uint2*)((char*)Pw + byte) = make_uint2(lo, hi);
      }
      bf16x8 pf[2];
#pragma unroll
      for (int ks = 0; ks < 2; ++ks) {
        const int byte = (frow * 128 + ks * 64 + fgrp * 16) ^ ((frow & 7) << 4);
        pf[ks] = *(const bf16x8*)((const char*)Pw + byte);
      }
#pragma unroll
      for (int te = 0; te < 4; ++te) {
        const int vrow = te * 16 + frow;  // V^T row = head-dim e
#pragma unroll
        for (int ks = 0; ks < 2; ++ks) {
          const int byte = (vrow * 128 + ks * 64 + fgrp * 16) ^ ((vrow & 7) << 4);
          const bf16x8 vf = *(const bf16x8*)((const char*)Vt[cur] + byte);
          accO[te] = __builtin_amdgcn_mfma_f32_16x16x32_bf16(pf[ks], vf, accO[te], 0, 0, 0);
        }
      }
      __syncthreads();  // drains vmcnt for staged loads; protects buffer swap
      cur ^= 1;
    }

    // epilogue: O /= l (l for row q=fgrp*4+r lives in lane frow=q), write bf16
    float lfin[4];
#pragma unroll
    for (int r = 0; r < 4; ++r) lfin[r] = __shfl(l_sc, fgrp * 4 + r, 64);
#pragma unroll
    for (int te = 0; te < 4; ++te)
#pragma unroll
      for (int r = 0; r < 4; ++r) {
        const float o = accO[te][r] / lfin[r];
        const int row = q0 + wid * 16 + fgrp * 4 + r;
        const int col = te * 16 + frow;
        attb[base_bh + (size_t)row * DM + col] = f2b(o);
      }
  }
}

extern "C" void kernel_launch(void* const* d_in, const int* in_sizes, int n_in,
                              void* d_out, int out_size, void* d_ws, size_t ws_size,
                              hipStream_t stream) {
  const float* x  = (const float*)d_in[0];
  const float* wq = (const float*)d_in[1];
  const float* wk = (const float*)d_in[2];
  const float* wv = (const float*)d_in[3];
  const float* wo = (const float*)d_in[4];
  const int* pos  = (const int*)d_in[5];
  float* out = (float*)d_out;
  (void)in_sizes; (void)n_in; (void)out_size; (void)ws_size;

  char* ws = (char*)d_ws;
  const size_t MB = 1024 * 1024;
  u16* xb   = (u16*)(ws);
  u16* wqb  = (u16*)(ws + 8 * MB);
  u16* wkb  = (u16*)(ws + 10 * MB);
  u16* wvb  = (u16*)(ws + 12 * MB);
  u16* wob  = (u16*)(ws + 14 * MB);
  u16* Qb   = (u16*)(ws + 16 * MB);
  u16* Kb   = (u16*)(ws + 24 * MB);
  u16* Vtb  = (u16*)(ws + 32 * MB);  // V^T: [1024][4096]
  u16* attb = (u16*)(ws + 40 * MB);

  cast_all<<<2048, 256, 0, stream>>>(x, wq, wk, wv, wo, xb, wqb, wkb, wvb, wob);
  gemm_qkvt<<<dim3(256, 1, 3), 256, 0, stream>>>(xb, wqb, wkb, wvb, Qb, Kb, Vtb);
  rope_kernel<<<2048, 256, 0, stream>>>(Qb, Kb, pos, BATCH * SEQ * NH * 32);
  attn_kernel<<<dim3(16, 32), 256, 0, stream>>>(Qb, Kb, Vtb, attb);
  gemm_o<<<dim3(8, 32), 256, 0, stream>>>(attb, wob, out);
}